// Round 8
// baseline (151.543 us; speedup 1.0000x reference)
//
#include <hip/hip_runtime.h>

#define BINS 10
#define TPB 256
#define MAX_BLOCKS 1024   // 4 blocks/CU; contiguous 64KB tile per block per array
#define NTHR 9            // bin thresholds k=1..9 in u-space
#define DEPTH 4           // forced in-flight load pairs per wave (8 loads)

typedef float f32x4 __attribute__((ext_vector_type(4)));
typedef int   i32x4 __attribute__((ext_vector_type(4)));

// u-space bin boundaries: c_k = ln(k / (9.9999 - k))  (logit of k/9.9999).
// bin(sigmoid(u)) >= k  <=>  u >= c_k   (sigmoid monotone).
__device__ __constant__ const float c_thr[NTHR] = {
    -2.1972135f, -1.3862819f, -0.8472836f, -0.4054484f, 2.00002e-5f,
     0.4054901f,  0.8473312f,  1.3863444f,  2.1973246f
};

// Register-resident suffix-histogram accumulate.
// A[0]  += ce (total);  A[k] += ce*(u>=c_k);  C[k-1] += (u>=c_k), k=1..9.
__device__ __forceinline__ void ghmc_accum(float z, int t, float* A, float* C) {
    // t in {0,1}:  g = |sigmoid(z)-t| = sigmoid(u),  ce = softplus(u),
    // with u = (t ? -z : z) = z with sign bit xor'd by t.
    unsigned ub = __float_as_uint(z) ^ ((unsigned)t << 31);
    float u  = __uint_as_float(ub);
    float e  = __expf(-fabsf(u));                  // v_mul + v_exp
    float q  = 1.0f + e;
    float ce = fmaxf(u, 0.0f) + __logf(q);         // v_max + v_log(+mul) + v_add
    A[0] += ce;
    #pragma unroll
    for (int k = 1; k <= NTHR; ++k) {
        float m = (u >= c_thr[k - 1]) ? 1.0f : 0.0f;  // v_cmp + v_cndmask
        A[k]    = fmaf(m, ce, A[k]);                  // v_fma
        C[k - 1] += m;                                // v_add
    }
}

// Inline-asm load pair: invisible to the compiler's waitcnt pass, so it
// cannot insert a pipeline-collapsing vmcnt(0); we count waits by hand.
#define ISSUE(xs, ts, idx) do {                                   \
    const f32x4* _xa = x4 + (idx);                                \
    const i32x4* _ta = t4 + (idx);                                \
    asm volatile("global_load_dwordx4 %0, %2, off\n\t"            \
                 "global_load_dwordx4 %1, %3, off"                \
                 : "=&v"(xs), "=&v"(ts)                           \
                 : "v"(_xa), "v"(_ta)                             \
                 : "memory");                                     \
} while (0)

#define COMPUTE(xs, ts) do {                                      \
    ghmc_accum((xs).x, (ts).x, A, C);                             \
    ghmc_accum((xs).y, (ts).y, A, C);                             \
    ghmc_accum((xs).z, (ts).z, A, C);                             \
    ghmc_accum((xs).w, (ts).w, A, C);                             \
} while (0)

// Counted wait + rule-#18 fence (compute must not hoist above the wait).
#define WAITV(n) do {                                             \
    asm volatile("s_waitcnt vmcnt(" #n ")" ::: "memory");         \
    __builtin_amdgcn_sched_barrier(0);                            \
} while (0)

__global__ __launch_bounds__(TPB, 4) void ghmc_main(const float* __restrict__ x,
                                                    const int* __restrict__ tgt,
                                                    float* __restrict__ partial,  // [gridDim.x][2*BINS]
                                                    int nvec, int ntotal) {
    float A[BINS];   // A[0]=total ce, A[k]=suffix ce-sum for threshold k
    float C[NTHR];   // suffix counts for thresholds 1..9
    #pragma unroll
    for (int b = 0; b < BINS; ++b) A[b] = 0.0f;
    #pragma unroll
    for (int k = 0; k < NTHR; ++k) C[k] = 0.0f;

    const f32x4* __restrict__ x4 = (const f32x4*)x;
    const i32x4* __restrict__ t4 = (const i32x4*)tgt;
    const int tid = threadIdx.x;
    const int nblocks = gridDim.x;
    // CONTIGUOUS TILES: block b owns vec4 range [b*TPB*nfull, (b+1)*TPB*nfull).
    // A wave's consecutive iterations step by TPB*16B = 4 KB (same 2MB page),
    // vs the old grid-stride's 2-8 MB jumps that made every CU walk every
    // page of both tensors (~128 translations/CU -> ~8 here).
    const int nfull   = nvec / (nblocks * TPB);   // = 16 for N=2^24, 1024 blocks
    const int covered = nblocks * TPB * nfull;
    const int tb = blockIdx.x * (TPB * nfull) + tid;  // tile base for this thread
    int it_done = 0;

    if (nfull >= DEPTH) {
        // Depth-4 software pipeline, 4 static slots (rule #20: no runtime
        // indexing -> slots stay in VGPRs). Issue order [s0,s0,s1,s1,...];
        // vmcnt(6) before slot s's compute guarantees s's pair landed;
        // reissue-after-compute keeps outstanding at 8. A slot's wait sits
        // ~3 compute phases (~1200 cy) after its issue > ~900 cy HBM latency.
        f32x4 xs0, xs1, xs2, xs3;
        i32x4 ts0, ts1, ts2, ts3;
        ISSUE(xs0, ts0, tb + 0 * TPB);
        ISSUE(xs1, ts1, tb + 1 * TPB);
        ISSUE(xs2, ts2, tb + 2 * TPB);
        ISSUE(xs3, ts3, tb + 3 * TPB);
        const int nchunk = nfull / DEPTH;      // = 4 for N=2^24
        int ip = DEPTH;                        // next iteration index to issue
        for (int c = 0; c < nchunk - 1; ++c) {
            WAITV(6); COMPUTE(xs0, ts0); ISSUE(xs0, ts0, tb + (ip + 0) * TPB);
            WAITV(6); COMPUTE(xs1, ts1); ISSUE(xs1, ts1, tb + (ip + 1) * TPB);
            WAITV(6); COMPUTE(xs2, ts2); ISSUE(xs2, ts2, tb + (ip + 2) * TPB);
            WAITV(6); COMPUTE(xs3, ts3); ISSUE(xs3, ts3, tb + (ip + 3) * TPB);
            ip += DEPTH;
        }
        // Drain: 6 -> 4 -> 2 -> 0 (never vmcnt(0) inside the loop).
        WAITV(6); COMPUTE(xs0, ts0);
        WAITV(4); COMPUTE(xs1, ts1);
        WAITV(2); COMPUTE(xs2, ts2);
        WAITV(0); COMPUTE(xs3, ts3);
        it_done = nchunk * DEPTH;
    }
    // Leftover full iterations (nfull % DEPTH, plus the nfull<DEPTH case).
    for (int it = it_done; it < nfull; ++it) {
        int g = tb + it * TPB;
        f32x4 xv = x4[g];
        i32x4 tv = t4[g];
        COMPUTE(xv, tv);
    }
    // Residual vec4 elements [covered, nvec) — grid-stride; no-op for N = 2^24.
    for (int g = covered + blockIdx.x * TPB + tid; g < nvec; g += nblocks * TPB) {
        f32x4 xv = x4[g];
        i32x4 tv = t4[g];
        COMPUTE(xv, tv);
    }
    // Scalar tail (N not a multiple of 4) — no-op for N = 2^24.
    if (blockIdx.x == 0) {
        for (int i = nvec * 4 + tid; i < ntotal; i += TPB)
            ghmc_accum(x[i], tgt[i], A, C);
    }

    // Wave-level shuffle reduce (64 lanes), then tiny LDS combine of the 4 waves.
    #pragma unroll
    for (int b = 0; b < BINS; ++b) {
        #pragma unroll
        for (int o = 32; o > 0; o >>= 1) A[b] += __shfl_down(A[b], o);
    }
    #pragma unroll
    for (int k = 0; k < NTHR; ++k) {
        #pragma unroll
        for (int o = 32; o > 0; o >>= 1) C[k] += __shfl_down(C[k], o);
    }
    __shared__ float red[TPB / 64][2 * BINS];   // 320 B — no occupancy impact
    const int wid = tid >> 6, lane = tid & 63;
    if (lane == 0) {
        #pragma unroll
        for (int b = 0; b < BINS; ++b) red[wid][b] = A[b];
        #pragma unroll
        for (int k = 0; k < NTHR; ++k) red[wid][BINS + k] = C[k];
    }
    __syncthreads();
    if (tid < BINS + NTHR) {
        float v = 0.0f;
        #pragma unroll
        for (int w = 0; w < TPB / 64; ++w) v += red[w][tid];
        partial[blockIdx.x * (2 * BINS) + tid] = v;   // per-block partials: no atomics
    }
}

// Recover per-bin sums/counts from suffix accumulators, then
// result = sum_b sum_ce_b / max(cnt_b * nonempty, 1e-6)   (the N in beta cancels)
__global__ __launch_bounds__(TPB) void ghmc_final(const float* __restrict__ partial,
                                                  float* __restrict__ out,
                                                  int nblocks, int ntotal) {
    float acc[2 * BINS];
    #pragma unroll
    for (int k = 0; k < 2 * BINS; ++k) acc[k] = 0.0f;
    for (int row = threadIdx.x; row < nblocks; row += TPB) {
        const float* p = partial + row * (2 * BINS);
        #pragma unroll
        for (int k = 0; k < 2 * BINS; ++k) acc[k] += p[k];
    }
    #pragma unroll
    for (int k = 0; k < 2 * BINS; ++k) {
        #pragma unroll
        for (int o = 32; o > 0; o >>= 1) acc[k] += __shfl_down(acc[k], o);
    }
    __shared__ float red[TPB / 64][2 * BINS];
    const int wid = threadIdx.x >> 6, lane = threadIdx.x & 63;
    if (lane == 0) {
        #pragma unroll
        for (int k = 0; k < 2 * BINS; ++k) red[wid][k] = acc[k];
    }
    __syncthreads();
    if (threadIdx.x == 0) {
        float A[BINS + 1], C[BINS + 1];
        #pragma unroll
        for (int b = 0; b < BINS; ++b) {
            float v = 0.0f;
            #pragma unroll
            for (int w = 0; w < TPB / 64; ++w) v += red[w][b];
            A[b] = v;
        }
        A[BINS] = 0.0f;
        C[0] = (float)ntotal;          // exact: ntotal <= 2^24
        #pragma unroll
        for (int k = 1; k <= NTHR; ++k) {
            float v = 0.0f;
            #pragma unroll
            for (int w = 0; w < TPB / 64; ++w) v += red[w][BINS + k - 1];
            C[k] = v;
        }
        C[BINS] = 0.0f;
        float ne = 0.0f;
        #pragma unroll
        for (int b = 0; b < BINS; ++b) {
            float c = C[b] - C[b + 1];
            ne += (c > 0.0f) ? 1.0f : 0.0f;
        }
        float res = 0.0f;
        #pragma unroll
        for (int b = 0; b < BINS; ++b) {
            float s = A[b] - A[b + 1];
            float c = C[b] - C[b + 1];
            res += s / fmaxf(c * ne, 1e-6f);
        }
        out[0] = res;
    }
}

extern "C" void kernel_launch(void* const* d_in, const int* in_sizes, int n_in,
                              void* d_out, int out_size, void* d_ws, size_t ws_size,
                              hipStream_t stream) {
    const float* x   = (const float*)d_in[0];
    const int*   tgt = (const int*)d_in[1];
    float* out     = (float*)d_out;
    float* partial = (float*)d_ws;

    int N    = in_sizes[0];
    int nvec = N / 4;

    int blocks = MAX_BLOCKS;
    int maxrows = (int)(ws_size / (2 * BINS * sizeof(float)));   // stay inside workspace
    if (blocks > maxrows) blocks = maxrows;
    int need = (nvec + TPB - 1) / TPB;
    if (blocks > need) blocks = need;
    if (blocks < 1) blocks = 1;

    ghmc_main<<<blocks, TPB, 0, stream>>>(x, tgt, partial, nvec, N);
    ghmc_final<<<1, TPB, 0, stream>>>(partial, out, blocks, N);
}